// Round 1
// baseline (318.433 us; speedup 1.0000x reference)
//
#include <hip/hip_runtime.h>
#include <math.h>
#include <limits.h>

#define B_  8
#define L_  128
#define VF_ 32128
#define V_  32100
#define D_  768

#define SEGS_ 4
#define NV4_  (VF_ / 4)   // 8032 float4s per row

typedef unsigned long long u64;

// Monotone map: f1 > f2  <=>  fmap(f1) > fmap(f2)  (inputs have no NaNs)
__device__ __forceinline__ unsigned int fmap(float f) {
    unsigned int u = __float_as_uint(f);
    return (u & 0x80000000u) ? ~u : (u | 0x80000000u);
}

// ---------------------------------------------------------------------------
// Kernel 1: segment argmax of logits+gumbel. Grid = 1024 rows x 4 segs,
// 256 threads. Each thread: 8 paired float4 loads (16 loads total, 256 B)
// with indices clamped to row end -- clamped lanes duplicate element 8031's
// (value,idx), harmless under max with first-index tie-break. All 16 loads
// issued before any compare (lp batch then gp batch; consumption order ==
// in-order vmcnt return order, so compares overlap the trailing gp loads).
// 128-VGPR cap (256,4): ~96 VGPRs needed for 16 in-flight loads -> fits.
// Per-block result -> plain store keys[row*4+seg] (no atomics, no memset).
// ---------------------------------------------------------------------------
__global__ __launch_bounds__(256, 4) void k_argmax(
    const float* __restrict__ logits, const float* __restrict__ gumbel,
    u64* __restrict__ keys)
{
    const int row = blockIdx.x >> 2;            // 0..1023
    const int seg = blockIdx.x & 3;             // 0..3
    const int tid = threadIdx.x;                // 0..255
    const size_t rowoff = (size_t)row * VF_;
    const float4* lp = (const float4*)(logits + rowoff);
    const float4* gp = (const float4*)(gumbel + rowoff);

    // segment = 2048 float4s; 8 chunks of 256
    int idx[8];
    #pragma unroll
    for (int k = 0; k < 8; ++k) {
        int i = (seg << 11) + (k << 8) + tid;
        idx[k] = (i < NV4_ - 1) ? i : (NV4_ - 1);
    }

    float4 A[8], G[8];
    #pragma unroll
    for (int k = 0; k < 8; ++k) A[k] = lp[idx[k]];
    #pragma unroll
    for (int k = 0; k < 8; ++k) G[k] = gp[idx[k]];

    float bv = -INFINITY;
    int   bi = 0;
    #pragma unroll
    for (int k = 0; k < 8; ++k) {
        float v;
        v = A[k].x + G[k].x; if (v > bv) { bv = v; bi = 4*idx[k] + 0; }
        v = A[k].y + G[k].y; if (v > bv) { bv = v; bi = 4*idx[k] + 1; }
        v = A[k].z + G[k].z; if (v > bv) { bv = v; bi = 4*idx[k] + 2; }
        v = A[k].w + G[k].w; if (v > bv) { bv = v; bi = 4*idx[k] + 3; }
    }

    // bigger value wins; equal value -> smaller idx (larger VF-idx) wins
    u64 k = ((u64)fmap(bv) << 32) | (u64)(VF_ - bi);
    for (int off = 32; off > 0; off >>= 1) {
        u64 o = __shfl_down(k, off, 64);
        if (o > k) k = o;
    }
    __shared__ u64 s_k[4];
    if ((tid & 63) == 0) s_k[tid >> 6] = k;
    __syncthreads();
    if (tid == 0) {
        u64 kk = s_k[0];
        if (s_k[1] > kk) kk = s_k[1];
        if (s_k[2] > kk) kk = s_k[2];
        if (s_k[3] > kk) kk = s_k[3];
        keys[blockIdx.x] = kk;
    }
}

// ---------------------------------------------------------------------------
// Kernel 2 (fused): per-(b,l) block. Merges the row's 4 segment keys,
// redundantly recomputes the per-b control logic (cheap: 256 int loads),
// then gathers the W row(s) into the output. 192 threads (768 floats / f4).
// ---------------------------------------------------------------------------
__global__ __launch_bounds__(192) void k_emb(
    const float* __restrict__ W,
    const int* __restrict__ rwrt, const int* __restrict__ psg,
    const u64* __restrict__ keys,
    float* __restrict__ out, float* __restrict__ nn_out)
{
    const int row = blockIdx.x;          // b*128 + l
    const int b = row >> 7;
    const int l = row & 127;
    const int t = threadIdx.x;           // 0..191

    __shared__ int s_att[L_];
    __shared__ int s_extr[L_];
    __shared__ u64 s_keys[SEGS_];
    __shared__ int s_len, s_first, s_rA, s_rB;

    if (t == 0) s_first = INT_MAX;
    if (t < L_) s_att[t] = rwrt[b * L_ + t];
    if (t >= 128 && t < 128 + SEGS_) s_keys[t - 128] = keys[row * SEGS_ + (t - 128)];
    __syncthreads();

    if (t == 0) {
        int len = 0;
        for (int i = 0; i < L_; ++i) len += (s_att[i] == 1);
        s_len = len;
    }
    if (t < L_) s_extr[t] = (1 - s_att[L_ - 1 - t]) * psg[b * L_ + t];
    __syncthreads();

    if (t < L_) {
        int src = (t - s_len + L_) & (L_ - 1);
        if (s_extr[src] != 0) atomicMin(&s_first, t);
    }
    __syncthreads();

    if (t == 0) {
        u64 kk = s_keys[0];
        #pragma unroll
        for (int i = 1; i < SEGS_; ++i) if (s_keys[i] > kk) kk = s_keys[i];
        const int am   = VF_ - (int)(kk & 0xFFFFFFFFull);
        const int srcl = (l - s_len + L_) & (L_ - 1);
        const int idxv = s_extr[srcl];
        const int flag = (l >= s_first) ? 1 : 0;
        const int rA = (s_att[l] == 1 && am < V_) ? am : -1;
        const int rB = flag ? idxv : -1;
        s_rA = rA; s_rB = rB;
        // Every realized row is exactly one W row (or zero): nn = its index.
        // Zero row -> all-zero sims -> jnp.argmax ties to 0.
        const int nn = (rA >= 0) ? rA : ((rB >= 0) ? rB : 0);
        nn_out[row] = (float)nn;
    }
    __syncthreads();

    const int rA = s_rA;
    const int rB = s_rB;
    float4 v = make_float4(0.f, 0.f, 0.f, 0.f);
    if (rA >= 0) {
        float4 a = ((const float4*)(W + (size_t)rA * D_))[t];
        v.x += a.x; v.y += a.y; v.z += a.z; v.w += a.w;
    }
    if (rB >= 0) {
        float4 a = ((const float4*)(W + (size_t)rB * D_))[t];
        v.x += a.x; v.y += a.y; v.z += a.z; v.w += a.w;
    }
    ((float4*)(out + (size_t)row * D_))[t] = v;
}

extern "C" void kernel_launch(void* const* d_in, const int* in_sizes, int n_in,
                              void* d_out, int out_size, void* d_ws, size_t ws_size,
                              hipStream_t stream)
{
    const float* logits = (const float*)d_in[0];
    const float* gumbel = (const float*)d_in[1];
    const float* W      = (const float*)d_in[2];
    const int*   rwrt   = (const int*)d_in[3];
    const int*   psg    = (const int*)d_in[4];

    float* out    = (float*)d_out;                       // embeds: 8*128*768
    float* nn_out = out + (size_t)B_ * L_ * D_;          // nn_idx as float: 1024

    u64* keys = (u64*)d_ws;                  // 4096 u64 segment keys (32 KB)

    k_argmax<<<B_ * L_ * SEGS_, 256, 0, stream>>>(logits, gumbel, keys);
    k_emb<<<B_ * L_, 192, 0, stream>>>(W, rwrt, psg, keys, out, nn_out);
}